// Round 13
// baseline (236.894 us; speedup 1.0000x reference)
//
#include <hip/hip_runtime.h>
#include <cstdint>

#define MARGIN_F 0.2f

typedef __attribute__((ext_vector_type(4))) float fv4;   // MFMA accumulator

// ---- async global->LDS, 16B per lane (dest = wave-uniform base + lane*16) ----
__device__ __forceinline__ void gload16(const void* g, void* l) {
    __builtin_amdgcn_global_load_lds(
        (const __attribute__((address_space(1))) unsigned*)g,
        (__attribute__((address_space(3))) unsigned*)l,
        16, 0, 0);
}

// =====================================================================
// prep: norms, d_pos (fp32 exact) + fp8 e4m3fn conversion of e1,e2
// grid: 4096 blocks x 128 threads (each thread: 4 floats of one row)
// =====================================================================
__global__ __launch_bounds__(128) void prep_kernel(
    const float* __restrict__ e1, const float* __restrict__ e2,
    unsigned* __restrict__ e1q, unsigned* __restrict__ e2q,   // 4 fp8 / uint
    float* __restrict__ n1, float* __restrict__ n2, float* __restrict__ dpos)
{
    const int row = blockIdx.x;
    const int t = threadIdx.x;
    const float4 a = reinterpret_cast<const float4*>(e1 + (size_t)row * 512)[t];
    const float4 b = reinterpret_cast<const float4*>(e2 + (size_t)row * 512)[t];

    int pa = __builtin_amdgcn_cvt_pk_fp8_f32(a.x, a.y, 0, false);
    pa     = __builtin_amdgcn_cvt_pk_fp8_f32(a.z, a.w, pa, true);
    int pb = __builtin_amdgcn_cvt_pk_fp8_f32(b.x, b.y, 0, false);
    pb     = __builtin_amdgcn_cvt_pk_fp8_f32(b.z, b.w, pb, true);
    e1q[row * 128 + t] = (unsigned)pa;
    e2q[row * 128 + t] = (unsigned)pb;

    float s1 = a.x*a.x + a.y*a.y + a.z*a.z + a.w*a.w;
    float s2 = b.x*b.x + b.y*b.y + b.z*b.z + b.w*b.w;
    float dx = a.x-b.x, dy = a.y-b.y, dz = a.z-b.z, dw = a.w-b.w;
    float sp = dx*dx + dy*dy + dz*dz + dw*dw;

    #pragma unroll
    for (int o = 32; o; o >>= 1) {
        s1 += __shfl_down(s1, o);
        s2 += __shfl_down(s2, o);
        sp += __shfl_down(sp, o);
    }
    __shared__ float r1[2], r2[2], rp[2];
    if ((t & 63) == 0) { int wv = t >> 6; r1[wv] = s1; r2[wv] = s2; rp[wv] = sp; }
    __syncthreads();
    if (t == 0) {
        n1[row] = r1[0] + r1[1];
        n2[row] = r2[0] + r2[1];
        dpos[row] = sqrtf(rp[0] + rp[1]);
    }
}

// =====================================================================
// main: ZERO-BARRIER wave-autonomous fp8 gram tiles.
// One 64-thread block = one wave = one 64x64 tile of one gram flavor:
//   bid < 4096 : G12 = e1 . e2^T, FULL 64x64 grid (D12 row + D21 col)
//   bid < 6176 : G11 triangle bi<=bj over 64 (row + sym col terms)
//   bid >= 6176: G22 triangle
// Per K-step (BK=64 fp8): wave stages its own 8KB (A 4KB + B 4KB) into a
// private 2x8KB LDS double-buffer via global_load_lds, paced by per-wave
// counted s_waitcnt vmcnt(8) — no __syncthreads anywhere. Stage of step
// t+2 issues between ds_reads and MFMAs of step t (latency hides under
// 32 MFMA). LDS 16B-slot swizzle u^=(row>>1)&3 -> 2-way banks (free).
// grid: 8256 blocks x 64 threads.
// =====================================================================
__global__ __launch_bounds__(64, 2) void triplet_main(
    const unsigned char* __restrict__ e1q, const unsigned char* __restrict__ e2q,
    const float* __restrict__ n1, const float* __restrict__ n2,
    const float* __restrict__ dpos,
    float* __restrict__ total, unsigned* __restrict__ count)
{
    __shared__ char lds[17408];        // 2 x 8KB staging + 1KB scalars
    float* scRN = (float*)(lds + 16384);
    float* scRD = (float*)(lds + 16640);
    float* scCN = (float*)(lds + 16896);
    float* scCD = (float*)(lds + 17152);

    // ---- flavor decode over 64x64 tiles ----
    const int bid = blockIdx.x;
    int bi, bj, flavor;                 // 0=G12 1=G11 2=G22
    if (bid < 4096) { flavor = 0; bi = bid >> 6; bj = bid & 63; }
    else {
        int b = bid - 4096; flavor = 1;
        if (b >= 2080) { b -= 2080; flavor = 2; }
        int r = (int)((129.0f - sqrtf(16641.0f - 8.0f * (float)b)) * 0.5f);
        while (64 * r - (r * (r - 1)) / 2 > b) --r;
        while (64 * (r + 1) - ((r + 1) * r) / 2 <= b) ++r;
        bi = r; bj = r + (b - (64 * r - (r * (r - 1)) / 2));
    }
    const int i0 = bi << 6, j0 = bj << 6;
    const char* Xp = (const char*)((flavor == 2) ? e2q : e1q) + (long)i0 * 512;
    const char* Yp = (const char*)((flavor == 1) ? e1q : e2q) + (long)j0 * 512;
    const float* nR = (flavor == 2) ? n2 : n1;
    const float* nC = (flavor == 1) ? n1 : n2;
    const bool emitCol = (flavor == 0) || (i0 != j0);
    const bool needNeq = (i0 == j0);

    const int lane = threadIdx.x;      // 0..63 (one wave)
    const int l15  = lane & 15;
    const int l4   = lane >> 4;

    // ---- scalars: wave-local LDS, no sync needed (same wave) ----
    scRN[lane] = nR[i0 + lane]; scRD[lane] = dpos[i0 + lane];
    scCN[lane] = nC[j0 + lane]; scCD[lane] = dpos[j0 + lane];
    __builtin_amdgcn_sched_barrier(0);

    // ---- staging offsets (pre-swizzled source; linear LDS dest) ----
    // LDS layout per buffer: A[64 rows][64B] at +0, B at +4096.
    // 16B slot u0 of row r holds logical slot u0 ^ ((r>>1)&3).
    int oS[4];
    #pragma unroll
    for (int c = 0; c < 4; ++c) {
        const int r = (c << 4) + (lane >> 2);
        const int u = (lane & 3) ^ ((r >> 1) & 3);
        oS[c] = r * 512 + (u << 4);
    }
    const int ldst = lane << 4;

#define STAGE(BSEL, T) do {                                                  \
    char* d_ = lds + ((BSEL) << 13);                                         \
    const long kb_ = (long)(T) << 6;                                         \
    _Pragma("unroll")                                                        \
    for (int c = 0; c < 4; ++c) {                                            \
        gload16(Xp + oS[c] + kb_, d_ + (c << 10) + ldst);                    \
        gload16(Yp + oS[c] + kb_, d_ + 4096 + (c << 10) + ldst);             \
    }                                                                        \
} while (0)

    // ---- swizzled ds_read offsets: row R, logical slot s=(kk<<1)|(l4>>1),
    //      8B half h=l4&1; stored slot = s ^ ((R>>1)&3) ----
    int ad[4][2];
    #pragma unroll
    for (int x = 0; x < 4; ++x) {
        const int R = (x << 4) + l15;
        #pragma unroll
        for (int kk = 0; kk < 2; ++kk) {
            const int s = (kk << 1) | (l4 >> 1);
            ad[x][kk] = R * 64 + (((s ^ ((R >> 1) & 3)) << 4) | ((l4 & 1) << 3));
        }
    }

    fv4 acc[4][4];
    #pragma unroll
    for (int m = 0; m < 4; ++m)
        #pragma unroll
        for (int n = 0; n < 4; ++n) acc[m][n] = (fv4)0.0f;

    // ---- prologue: prefetch steps 0,1 (8 loads each) ----
    STAGE(0, 0);
    STAGE(1, 1);

    // ---- barrier-free pipelined K-loop: 8 steps of BK=64 ----
    #pragma unroll
    for (int t = 0; t < 8; ++t) {
        if (t < 7) asm volatile("s_waitcnt vmcnt(8)" ::: "memory"); // step t landed
        else       asm volatile("s_waitcnt vmcnt(0)" ::: "memory"); // tail drain
        __builtin_amdgcn_sched_barrier(0);

        const char* base_ = lds + ((t & 1) << 13);
        long a0_[4], a1_[4], b0_[4], b1_[4];
        #pragma unroll
        for (int x = 0; x < 4; ++x) {
            a0_[x] = *(const long*)(base_ + ad[x][0]);
            a1_[x] = *(const long*)(base_ + ad[x][1]);
            b0_[x] = *(const long*)(base_ + 4096 + ad[x][0]);
            b1_[x] = *(const long*)(base_ + 4096 + ad[x][1]);
        }
        // reads retired -> safe to overwrite this buffer; issue next stage
        asm volatile("s_waitcnt lgkmcnt(0)" ::: "memory");
        __builtin_amdgcn_sched_barrier(0);
        if (t + 2 < 8) STAGE(t & 1, t + 2);
        __builtin_amdgcn_sched_barrier(0);

        #pragma unroll
        for (int m = 0; m < 4; ++m)
            #pragma unroll
            for (int n = 0; n < 4; ++n) {
                acc[m][n] = __builtin_amdgcn_mfma_f32_16x16x32_fp8_fp8(
                    a0_[m], b0_[n], acc[m][n], 0, 0, 0);
                acc[m][n] = __builtin_amdgcn_mfma_f32_16x16x32_fp8_fp8(
                    a1_[m], b1_[n], acc[m][n], 0, 0, 0);
            }
    }
#undef STAGE

    // ---- fused epilogue (sqrt-domain): C/D col=lane&15, row=(lane>>4)*4+rr --
    float    ltot = 0.0f;
    unsigned lcnt = 0;

    float cN_[4], cD_[4], cM_[4];
    #pragma unroll
    for (int n = 0; n < 4; ++n) {
        const int cl = (n << 4) + l15;
        cN_[n] = scCN[cl]; cD_[n] = scCD[cl]; cM_[n] = cD_[n] + MARGIN_F;
    }

    #pragma unroll
    for (int m = 0; m < 4; ++m) {
        #pragma unroll
        for (int rr = 0; rr < 4; ++rr) {
            const int rl = (m << 4) + (l4 << 2) + rr;
            const float rN = scRN[rl], rD = scRD[rl], rM = rD + MARGIN_F;
            #pragma unroll
            for (int n = 0; n < 4; ++n) {
                const int cl = (n << 4) + l15;
                const float s = sqrtf(fmaxf(fmaf(-2.0f, acc[m][n][rr], rN + cN_[n]), 0.0f));
                const bool neq = (!needNeq) || (rl != cl);
                bool c1 = neq && (rD < s);
                lcnt += c1; ltot += c1 ? fmaxf(rM - s, 0.0f) : 0.0f;
                bool c2 = emitCol && neq && (cD_[n] < s);
                lcnt += c2; ltot += c2 ? fmaxf(cM_[n] - s, 0.0f) : 0.0f;
            }
        }
    }

    // ---- wave reduction -> one atomic pair per block ----
    #pragma unroll
    for (int o = 32; o; o >>= 1) {
        ltot += __shfl_down(ltot, o);
        lcnt += __shfl_down(lcnt, o);
    }
    if (lane == 0) {
        atomicAdd(total, ltot);
        atomicAdd(count, lcnt);
    }
}

__global__ void finalize_kernel(const float* __restrict__ total,
                                const unsigned* __restrict__ count,
                                float* __restrict__ out)
{
    out[0] = total[0] / fmaxf((float)count[0], 1.0f);
}

// =====================================================================
// Workspace layout (~4.5 MB):
//   [0,8)        : total (f32), count (u32)
//   [1024, ...)  : n1[4096], n2[4096], dpos[4096]  (f32)
//   [131072, ..) : e1q 4096x512 fp8 (2MB), then e2q (2MB)
// =====================================================================
extern "C" void kernel_launch(void* const* d_in, const int* in_sizes, int n_in,
                              void* d_out, int out_size, void* d_ws, size_t ws_size,
                              hipStream_t stream) {
    const float* e1 = (const float*)d_in[0];
    const float* e2 = (const float*)d_in[1];
    char* ws = (char*)d_ws;

    float*    total = (float*)ws;
    unsigned* count = (unsigned*)(ws + 4);
    float* n1   = (float*)(ws + 1024);
    float* n2   = n1 + 4096;
    float* dpos = n2 + 4096;
    unsigned* e1q = (unsigned*)(ws + (1 << 17));
    unsigned* e2q = e1q + (size_t)4096 * 128;

    hipMemsetAsync(ws, 0, 64, stream);
    prep_kernel<<<4096, 128, 0, stream>>>(e1, e2, e1q, e2q, n1, n2, dpos);
    triplet_main<<<8256, 64, 0, stream>>>((const unsigned char*)e1q,
                                          (const unsigned char*)e2q,
                                          n1, n2, dpos, total, count);
    finalize_kernel<<<1, 1, 0, stream>>>(total, count, (float*)d_out);
}

// Round 14
// 81.664 us; speedup vs baseline: 2.9009x; 2.9009x over previous
//
#include <hip/hip_runtime.h>
#include <cstdint>

#define MARGIN_F 0.2f

typedef __attribute__((ext_vector_type(4))) float fv4;   // MFMA accumulator
typedef __attribute__((ext_vector_type(2))) long lv2;    // 16B = 2 x i64 (fp8 frag pair)

// ---- async global->LDS, 16B per lane (dest = wave-uniform base + lane*16) ----
__device__ __forceinline__ void gload16(const void* g, void* l) {
    __builtin_amdgcn_global_load_lds(
        (const __attribute__((address_space(1))) unsigned*)g,
        (__attribute__((address_space(3))) unsigned*)l,
        16, 0, 0);
}

// =====================================================================
// prep: norms, d_pos (fp32 exact) + fp8 e4m3fn conversion of e1,e2.
// fp8 written in PERMUTED order within each 128B K-window so that the
// main kernel can read one b128 per lane per MFMA-pair (R8's proven
// zero-conflict pattern): source 8B block b (kk=b>>2, l4=b&3) goes to
// block tb = ((b>>3)<<3) | ((b&3)<<1) | ((b>>2)&1).
// grid: 4096 blocks x 128 threads (each thread: 4 floats of one row)
// =====================================================================
__global__ __launch_bounds__(128) void prep_kernel(
    const float* __restrict__ e1, const float* __restrict__ e2,
    unsigned* __restrict__ e1q, unsigned* __restrict__ e2q,   // 4 fp8 / uint
    float* __restrict__ n1, float* __restrict__ n2, float* __restrict__ dpos)
{
    const int row = blockIdx.x;
    const int t = threadIdx.x;
    const float4 a = reinterpret_cast<const float4*>(e1 + (size_t)row * 512)[t];
    const float4 b = reinterpret_cast<const float4*>(e2 + (size_t)row * 512)[t];

    int pa = __builtin_amdgcn_cvt_pk_fp8_f32(a.x, a.y, 0, false);
    pa     = __builtin_amdgcn_cvt_pk_fp8_f32(a.z, a.w, pa, true);
    int pb = __builtin_amdgcn_cvt_pk_fp8_f32(b.x, b.y, 0, false);
    pb     = __builtin_amdgcn_cvt_pk_fp8_f32(b.z, b.w, pb, true);

    // permuted destination (uint granularity) within the row
    const int wq    = t >> 5;          // 128B window 0..3
    const int u     = t & 31;          // uint slot in window
    const int blk   = u >> 1;          // 8B block 0..15
    const int piece = u & 1;
    const int tb    = ((blk >> 3) << 3) | ((blk & 3) << 1) | ((blk >> 2) & 1);
    const int di    = (wq << 5) + (tb << 1) + piece;
    e1q[row * 128 + di] = (unsigned)pa;
    e2q[row * 128 + di] = (unsigned)pb;

    float s1 = a.x*a.x + a.y*a.y + a.z*a.z + a.w*a.w;
    float s2 = b.x*b.x + b.y*b.y + b.z*b.z + b.w*b.w;
    float dx = a.x-b.x, dy = a.y-b.y, dz = a.z-b.z, dw = a.w-b.w;
    float sp = dx*dx + dy*dy + dz*dz + dw*dw;

    #pragma unroll
    for (int o = 32; o; o >>= 1) {
        s1 += __shfl_down(s1, o);
        s2 += __shfl_down(s2, o);
        sp += __shfl_down(sp, o);
    }
    __shared__ float r1[2], r2[2], rp[2];
    if ((t & 63) == 0) { int wv = t >> 6; r1[wv] = s1; r2[wv] = s2; rp[wv] = sp; }
    __syncthreads();
    if (t == 0) {
        n1[row] = r1[0] + r1[1];
        n2[row] = r2[0] + r2[1];
        dpos[row] = sqrtf(rp[0] + rp[1]);
    }
}

// =====================================================================
// main: R12 structure (m97-faithful schedule, fp8 128x128 flavor tiles)
// with (a) b128 fragment reads via prep's permuted layout + R8 swizzle
// (zero bank conflicts), (b) lean specialized epilogue with 1-inst sqrt.
//   bid <  1024 : G12 = e1 . e2^T, FULL 32x32 grid (D12 row + D21 col)
//   bid <  1552 : G11 triangle bi<=bj (row + sym col terms)
//   bid >= 1552 : G22 triangle
// grid: 2080 blocks x 256 threads (4 waves 2x2; wave region 64x64).
// =====================================================================
__global__ __launch_bounds__(256, 3) void triplet_main(
    const unsigned char* __restrict__ e1q, const unsigned char* __restrict__ e2q,
    const float* __restrict__ n1, const float* __restrict__ n2,
    const float* __restrict__ dpos,
    float* __restrict__ total, unsigned* __restrict__ count)
{
    __shared__ char buf[32768];        // A tile [0,16K) | B tile [16K,32K)
    __shared__ float scRN[128], scRD[128], scCN[128], scCD[128];
    __shared__ float lt[4];
    __shared__ unsigned lc[4];

    // ---- flavor decode (R8/R12 order) ----
    const int bid = blockIdx.x;
    int bi, bj, flavor;                 // 0=G12 1=G11 2=G22
    if (bid < 1024) { flavor = 0; bi = bid >> 5; bj = bid & 31; }
    else {
        int b = bid - 1024; flavor = 1;
        if (b >= 528) { b -= 528; flavor = 2; }
        int r = (int)((65.0f - sqrtf(4225.0f - 8.0f * (float)b)) * 0.5f);
        while (32 * r - (r * (r - 1)) / 2 > b) --r;
        while (32 * (r + 1) - ((r + 1) * r) / 2 <= b) ++r;
        bi = r; bj = r + (b - (32 * r - (r * (r - 1)) / 2));
    }
    const int i0 = bi << 7, j0 = bj << 7;
    const char* Xc = (const char*)((flavor == 2) ? e2q : e1q);   // i-side rows
    const char* Yc = (const char*)((flavor == 1) ? e1q : e2q);   // j-side rows
    const float* nR = (flavor == 2) ? n2 : n1;
    const float* nC = (flavor == 1) ? n1 : n2;
    const bool emitCol = (flavor == 0) || (i0 != j0);
    const bool needNeq = (i0 == j0);

    const int tid  = threadIdx.x;
    const int w    = tid >> 6;
    const int lane = tid & 63;
    const int l15  = lane & 15;
    const int l4   = lane >> 4;
    const int wr   = w >> 1;      // 0..1
    const int wc   = w & 1;       // 0..1

    // ---- epilogue scalar preload ----
    if (tid < 128)      { scRN[tid] = nR[i0 + tid]; scRD[tid] = dpos[i0 + tid]; }
    else { const int t = tid - 128; scCN[t] = nC[j0 + t]; scCD[t] = dpos[j0 + t]; }

    // ---- staging addresses (fp8 row = 512B; K-step window = 128B) ----
    long srcA[4];
    #pragma unroll
    for (int c = 0; c < 4; ++c) {
        const int chA = tid + (c << 8);              // 0..1023
        const int rA  = chA >> 3;                    // 0..127
        srcA[c] = (long)(i0 + rA) * 512 + (((chA & 7) << 4) ^ ((rA & 7) << 4));
    }
    const long jd = (long)(j0 - i0) * 512;           // B source delta (uniform)
    const int ldst = w << 10;                        // wave-uniform dest part

    // ---- R8-style zero-conflict swizzled b128 read bases; khalf = ^64 ----
    const int slot = (l4 << 4) ^ ((l15 & 7) << 4);
    const int aB = ((wr << 6) + l15) * 128 + slot;
    const int bB = 16384 + ((wc << 6) + l15) * 128 + slot;

    fv4 acc[4][4];
    #pragma unroll
    for (int m = 0; m < 4; ++m)
        #pragma unroll
        for (int n = 0; n < 4; ++n) acc[m][n] = (fv4)0.0f;

    // ---- m97 loop: stage -> sync -> compute(2 halves x 2 kk) -> sync ----
    for (int t = 0; t < 4; ++t) {
        const long kb = (long)t << 7;                // 128B K-window per step
        #pragma unroll
        for (int c = 0; c < 4; ++c) {
            gload16(Xc + srcA[c] + kb,      buf + (c << 12) + ldst);
            gload16(Yc + srcA[c] + jd + kb, buf + 16384 + (c << 12) + ldst);
        }
        __syncthreads();
        #pragma unroll
        for (int h = 0; h < 2; ++h) {
            const int H = h << 6;
            lv2 a_[4], b_[4];
            #pragma unroll
            for (int m = 0; m < 4; ++m)
                a_[m] = *(const lv2*)(buf + ((aB + m * 2048) ^ H));
            #pragma unroll
            for (int n = 0; n < 4; ++n)
                b_[n] = *(const lv2*)(buf + ((bB + n * 2048) ^ H));
            #pragma unroll
            for (int m = 0; m < 4; ++m)
                #pragma unroll
                for (int n = 0; n < 4; ++n) {
                    acc[m][n] = __builtin_amdgcn_mfma_f32_16x16x32_fp8_fp8(
                        a_[m][0], b_[n][0], acc[m][n], 0, 0, 0);
                    acc[m][n] = __builtin_amdgcn_mfma_f32_16x16x32_fp8_fp8(
                        a_[m][1], b_[n][1], acc[m][n], 0, 0, 0);
                }
        }
        __syncthreads();
    }

    // ---- lean fused epilogue (sqrt-domain, specialized) ----
    float    ltot = 0.0f;
    unsigned lcnt = 0;

#define EPI(EMITCOL, NEEDNEQ) do {                                           \
    float cN_[4], cM_[4];                                                    \
    _Pragma("unroll")                                                        \
    for (int n = 0; n < 4; ++n) {                                            \
        const int cl = (wc << 6) + (n << 4) + l15;                           \
        cN_[n] = scCN[cl]; cM_[n] = scCD[cl] + MARGIN_F;                     \
    }                                                                        \
    _Pragma("unroll")                                                        \
    for (int m = 0; m < 4; ++m) {                                            \
        _Pragma("unroll")                                                    \
        for (int rr = 0; rr < 4; ++rr) {                                     \
            const int rl = (wr << 6) + (m << 4) + (l4 << 2) + rr;            \
            const float rN = scRN[rl];                                       \
            const float rM = scRD[rl] + MARGIN_F;                            \
            _Pragma("unroll")                                                \
            for (int n = 0; n < 4; ++n) {                                    \
                const float D = fmaxf(fmaf(-2.0f, acc[m][n][rr],             \
                                           rN + cN_[n]), 0.0f);              \
                const float s = __builtin_amdgcn_sqrtf(D);                   \
                bool neq = true;                                             \
                if (NEEDNEQ) neq = (rl != ((wc << 6) + (n << 4) + l15));     \
                const float t1 = rM - s;                                     \
                const bool c1 = (t1 < MARGIN_F) && neq;                      \
                lcnt += c1;                                                  \
                ltot += c1 ? fmaxf(t1, 0.0f) : 0.0f;                         \
                if (EMITCOL) {                                               \
                    const float t2 = cM_[n] - s;                             \
                    const bool c2 = (t2 < MARGIN_F) && neq;                  \
                    lcnt += c2;                                              \
                    ltot += c2 ? fmaxf(t2, 0.0f) : 0.0f;                     \
                }                                                            \
            }                                                                \
        }                                                                    \
    }                                                                        \
} while (0)

    if (!needNeq)      EPI(true, false);    // hot: 1984 / 2080 blocks
    else if (emitCol)  EPI(true, true);     // G12 diag tiles
    else               EPI(false, true);    // G11/G22 diag tiles
#undef EPI

    // ---- block reduction: wave shuffle -> LDS -> one atomic pair ----
    #pragma unroll
    for (int o = 32; o; o >>= 1) {
        ltot += __shfl_down(ltot, o);
        lcnt += __shfl_down(lcnt, o);
    }
    if (lane == 0) { lt[w] = ltot; lc[w] = lcnt; }
    __syncthreads();
    if (tid == 0) {
        float T = 0.0f; unsigned C = 0;
        #pragma unroll
        for (int x = 0; x < 4; ++x) { T += lt[x]; C += lc[x]; }
        atomicAdd(total, T);
        atomicAdd(count, C);
    }
}

__global__ void finalize_kernel(const float* __restrict__ total,
                                const unsigned* __restrict__ count,
                                float* __restrict__ out)
{
    out[0] = total[0] / fmaxf((float)count[0], 1.0f);
}

// =====================================================================
// Workspace layout (~4.5 MB):
//   [0,8)        : total (f32), count (u32)
//   [1024, ...)  : n1[4096], n2[4096], dpos[4096]  (f32)
//   [131072, ..) : e1q 4096x512 fp8 (2MB), then e2q (2MB)
// =====================================================================
extern "C" void kernel_launch(void* const* d_in, const int* in_sizes, int n_in,
                              void* d_out, int out_size, void* d_ws, size_t ws_size,
                              hipStream_t stream) {
    const float* e1 = (const float*)d_in[0];
    const float* e2 = (const float*)d_in[1];
    char* ws = (char*)d_ws;

    float*    total = (float*)ws;
    unsigned* count = (unsigned*)(ws + 4);
    float* n1   = (float*)(ws + 1024);
    float* n2   = n1 + 4096;
    float* dpos = n2 + 4096;
    unsigned* e1q = (unsigned*)(ws + (1 << 17));
    unsigned* e2q = e1q + (size_t)4096 * 128;

    hipMemsetAsync(ws, 0, 64, stream);
    prep_kernel<<<4096, 128, 0, stream>>>(e1, e2, e1q, e2q, n1, n2, dpos);
    triplet_main<<<2080, 256, 0, stream>>>((const unsigned char*)e1q,
                                           (const unsigned char*)e2q,
                                           n1, n2, dpos, total, count);
    finalize_kernel<<<1, 1, 0, stream>>>(total, count, (float*)d_out);
}

// Round 15
// 67.979 us; speedup vs baseline: 3.4848x; 1.2013x over previous
//
#include <hip/hip_runtime.h>
#include <cstdint>

#define MARGIN_F 0.2f

typedef __attribute__((ext_vector_type(4))) float fv4;   // MFMA accumulator
typedef __attribute__((ext_vector_type(2))) long lv2;    // 16B = 2 x i64 (fp8 frag pair)

// ---- async global->LDS, 16B per lane (dest = wave-uniform base + lane*16) ----
__device__ __forceinline__ void gload16(const void* g, void* l) {
    __builtin_amdgcn_global_load_lds(
        (const __attribute__((address_space(1))) unsigned*)g,
        (__attribute__((address_space(3))) unsigned*)l,
        16, 0, 0);
}

// =====================================================================
// prep: norms, d_pos (fp32 exact) + fp8 e4m3fn conversion of e1,e2.
// fp8 written in PERMUTED order within each 128B K-window so the main
// kernel reads one b128 per lane per MFMA-pair (R8's zero-conflict
// pattern): source 8B block b (kk=b>>2, l4=b&3) goes to block
// tb = ((b>>3)<<3) | ((b&3)<<1) | ((b>>2)&1).
// grid: 4096 blocks x 128 threads (each thread: 4 floats of one row)
// =====================================================================
__global__ __launch_bounds__(128) void prep_kernel(
    const float* __restrict__ e1, const float* __restrict__ e2,
    unsigned* __restrict__ e1q, unsigned* __restrict__ e2q,   // 4 fp8 / uint
    float* __restrict__ n1, float* __restrict__ n2, float* __restrict__ dpos)
{
    const int row = blockIdx.x;
    const int t = threadIdx.x;
    const float4 a = reinterpret_cast<const float4*>(e1 + (size_t)row * 512)[t];
    const float4 b = reinterpret_cast<const float4*>(e2 + (size_t)row * 512)[t];

    int pa = __builtin_amdgcn_cvt_pk_fp8_f32(a.x, a.y, 0, false);
    pa     = __builtin_amdgcn_cvt_pk_fp8_f32(a.z, a.w, pa, true);
    int pb = __builtin_amdgcn_cvt_pk_fp8_f32(b.x, b.y, 0, false);
    pb     = __builtin_amdgcn_cvt_pk_fp8_f32(b.z, b.w, pb, true);

    // permuted destination (uint granularity) within the row
    const int wq    = t >> 5;          // 128B window 0..3
    const int u     = t & 31;          // uint slot in window
    const int blk   = u >> 1;          // 8B block 0..15
    const int piece = u & 1;
    const int tb    = ((blk >> 3) << 3) | ((blk & 3) << 1) | ((blk >> 2) & 1);
    const int di    = (wq << 5) + (tb << 1) + piece;
    e1q[row * 128 + di] = (unsigned)pa;
    e2q[row * 128 + di] = (unsigned)pb;

    float s1 = a.x*a.x + a.y*a.y + a.z*a.z + a.w*a.w;
    float s2 = b.x*b.x + b.y*b.y + b.z*b.z + b.w*b.w;
    float dx = a.x-b.x, dy = a.y-b.y, dz = a.z-b.z, dw = a.w-b.w;
    float sp = dx*dx + dy*dy + dz*dz + dw*dw;

    #pragma unroll
    for (int o = 32; o; o >>= 1) {
        s1 += __shfl_down(s1, o);
        s2 += __shfl_down(s2, o);
        sp += __shfl_down(sp, o);
    }
    __shared__ float r1[2], r2[2], rp[2];
    if ((t & 63) == 0) { int wv = t >> 6; r1[wv] = s1; r2[wv] = s2; rp[wv] = sp; }
    __syncthreads();
    if (t == 0) {
        n1[row] = r1[0] + r1[1];
        n2[row] = r2[0] + r2[1];
        dpos[row] = sqrtf(rp[0] + rp[1]);
    }
}

// =====================================================================
// main: R14 fp8 kernel with MULTI-TILE BLOCKS (R11 mechanics):
// one block = one i-panel x run of up to 4 consecutive j-tiles (128^2).
//   bid <  256 : G12 (bi = bid>>3, j-run (bid&7)*4, 4 tiles)
//   bid <  400 : G11 triangle rows, runs of <=4 (144 blocks)
//   bid >= 400 : G22 triangle rows, runs of <=4 (144 blocks)
// Next tile's step-0 stage issues BEFORE the current tile's epilogue
// (latency hides under epilogue VALU); one prologue/reduction per run.
// grid: 544 blocks x 256 threads (4 waves 2x2; wave region 64x64).
// =====================================================================
__global__ __launch_bounds__(256, 3) void triplet_main(
    const unsigned char* __restrict__ e1q, const unsigned char* __restrict__ e2q,
    const float* __restrict__ n1, const float* __restrict__ n2,
    const float* __restrict__ dpos,
    float* __restrict__ total, unsigned* __restrict__ count)
{
    __shared__ char buf[32768];        // A tile [0,16K) | B tile [16K,32K)
    __shared__ float scRN[128], scRD[128], scCN[128], scCD[128];
    __shared__ float lt[4];
    __shared__ unsigned lc[4];

    // ---- decode: (flavor, bi, bjStart, ntiles) ----
    const int bid = blockIdx.x;
    int bi, bjStart, ntiles, flavor;    // 0=G12 1=G11 2=G22
    if (bid < 256) {
        flavor = 0; bi = bid >> 3; bjStart = (bid & 7) << 2; ntiles = 4;
    } else {
        int b = bid - 256; flavor = 1;
        if (b >= 144) { b -= 144; flavor = 2; }
        int r = 0;
        while (b >= ((35 - r) >> 2)) { b -= (35 - r) >> 2; ++r; }
        bi = r; bjStart = r + (b << 2);
        ntiles = 32 - bjStart; if (ntiles > 4) ntiles = 4;
    }
    const int i0 = bi << 7;
    const char* Xc = (const char*)((flavor == 2) ? e2q : e1q);   // i-side rows
    const char* Yc = (const char*)((flavor == 1) ? e1q : e2q);   // j-side rows
    const float* nR = (flavor == 2) ? n2 : n1;
    const float* nC = (flavor == 1) ? n1 : n2;

    const int tid  = threadIdx.x;
    const int w    = tid >> 6;
    const int lane = tid & 63;
    const int l15  = lane & 15;
    const int l4   = lane >> 4;
    const int wr   = w >> 1;      // 0..1
    const int wc   = w & 1;       // 0..1

    // ---- staging addresses (fp8 row = 512B; K-step window = 128B) ----
    long srcA[4];
    #pragma unroll
    for (int c = 0; c < 4; ++c) {
        const int chA = tid + (c << 8);              // 0..1023
        const int rA  = chA >> 3;                    // 0..127
        srcA[c] = (long)(i0 + rA) * 512 + (((chA & 7) << 4) ^ ((rA & 7) << 4));
    }
    const int ldst = w << 10;                        // wave-uniform dest part

#define STAGE(T, JD) do {                                                    \
    const long kb_ = (long)(T) << 7;                                         \
    _Pragma("unroll")                                                        \
    for (int c = 0; c < 4; ++c) {                                            \
        gload16(Xc + srcA[c] + kb_,        buf + (c << 12) + ldst);          \
        gload16(Yc + srcA[c] + (JD) + kb_, buf + 16384 + (c << 12) + ldst);  \
    }                                                                        \
} while (0)

    // ---- R8-style zero-conflict swizzled b128 read bases; khalf = ^64 ----
    const int slot = (l4 << 4) ^ ((l15 & 7) << 4);
    const int aB = ((wr << 6) + l15) * 128 + slot;
    const int bB = 16384 + ((wc << 6) + l15) * 128 + slot;

#define EPI(EMITCOL, NEEDNEQ) do {                                           \
    float cN_[4], cM_[4];                                                    \
    _Pragma("unroll")                                                        \
    for (int n = 0; n < 4; ++n) {                                            \
        const int cl = (wc << 6) + (n << 4) + l15;                           \
        cN_[n] = scCN[cl]; cM_[n] = scCD[cl] + MARGIN_F;                     \
    }                                                                        \
    _Pragma("unroll")                                                        \
    for (int m = 0; m < 4; ++m) {                                            \
        _Pragma("unroll")                                                    \
        for (int rr = 0; rr < 4; ++rr) {                                     \
            const int rl = (wr << 6) + (m << 4) + (l4 << 2) + rr;            \
            const float rN = scRN[rl];                                       \
            const float rM = scRD[rl] + MARGIN_F;                            \
            _Pragma("unroll")                                                \
            for (int n = 0; n < 4; ++n) {                                    \
                const float D = fmaxf(fmaf(-2.0f, acc[m][n][rr],             \
                                           rN + cN_[n]), 0.0f);              \
                const float s = __builtin_amdgcn_sqrtf(D);                   \
                bool neq = true;                                             \
                if (NEEDNEQ) neq = (rl != ((wc << 6) + (n << 4) + l15));     \
                const float t1 = rM - s;                                     \
                const bool c1 = (t1 < MARGIN_F) && neq;                      \
                lcnt += c1;                                                  \
                ltot += c1 ? fmaxf(t1, 0.0f) : 0.0f;                         \
                if (EMITCOL) {                                               \
                    const float t2 = cM_[n] - s;                             \
                    const bool c2 = (t2 < MARGIN_F) && neq;                  \
                    lcnt += c2;                                              \
                    ltot += c2 ? fmaxf(t2, 0.0f) : 0.0f;                     \
                }                                                            \
            }                                                                \
        }                                                                    \
    }                                                                        \
} while (0)

    // ---- prologue: scalars + first stage ----
    const int j0first = bjStart << 7;
    if (tid < 128)      { scRN[tid] = nR[i0 + tid]; scRD[tid] = dpos[i0 + tid]; }
    else { const int t = tid - 128; scCN[t] = nC[j0first + t]; scCD[t] = dpos[j0first + t]; }
    STAGE(0, (long)(j0first - i0) * 512);

    float    ltot = 0.0f;
    unsigned lcnt = 0;
    fv4 acc[4][4];

    for (int tt = 0; tt < ntiles; ++tt) {
        const int j0   = (bjStart + tt) << 7;
        const long jd  = (long)(j0 - i0) * 512;
        const bool last = (tt + 1 >= ntiles);
        const bool needNeq = (i0 == j0);

        #pragma unroll
        for (int m = 0; m < 4; ++m)
            #pragma unroll
            for (int n = 0; n < 4; ++n) acc[m][n] = (fv4)0.0f;

        // ---- K-loop: sync(stage landed) -> compute -> sync -> stage next --
        for (int t = 0; t < 4; ++t) {
            __syncthreads();
            #pragma unroll
            for (int h = 0; h < 2; ++h) {
                const int H = h << 6;
                lv2 a_[4], b_[4];
                #pragma unroll
                for (int m = 0; m < 4; ++m)
                    a_[m] = *(const lv2*)(buf + ((aB + m * 2048) ^ H));
                #pragma unroll
                for (int n = 0; n < 4; ++n)
                    b_[n] = *(const lv2*)(buf + ((bB + n * 2048) ^ H));
                #pragma unroll
                for (int m = 0; m < 4; ++m)
                    #pragma unroll
                    for (int n = 0; n < 4; ++n) {
                        acc[m][n] = __builtin_amdgcn_mfma_f32_16x16x32_fp8_fp8(
                            a_[m][0], b_[n][0], acc[m][n], 0, 0, 0);
                        acc[m][n] = __builtin_amdgcn_mfma_f32_16x16x32_fp8_fp8(
                            a_[m][1], b_[n][1], acc[m][n], 0, 0, 0);
                    }
            }
            __syncthreads();
            if (t < 3)      STAGE(t + 1, jd);
            else if (!last) STAGE(0, jd + 65536);   // next tile; hides under epilogue
        }

        // ---- lean specialized epilogue for this tile ----
        if (!needNeq)           EPI(true, false);   // hot path
        else if (flavor == 0)   EPI(true, true);    // G12 diag tiles
        else                    EPI(false, true);   // G11/G22 diag tiles

        // ---- swap in next tile's j-side scalars (behind barrier) ----
        if (!last) {
            __syncthreads();            // epilogue scalar reads complete
            if (tid >= 128) {
                const int t2 = tid - 128;
                scCN[t2] = nC[j0 + 128 + t2]; scCD[t2] = dpos[j0 + 128 + t2];
            }
            // next K-loop's first __syncthreads publishes these writes
        }
    }
#undef STAGE
#undef EPI

    // ---- block reduction: wave shuffle -> LDS -> one atomic pair ----
    #pragma unroll
    for (int o = 32; o; o >>= 1) {
        ltot += __shfl_down(ltot, o);
        lcnt += __shfl_down(lcnt, o);
    }
    __syncthreads();
    if (lane == 0) { lt[w] = ltot; lc[w] = lcnt; }
    __syncthreads();
    if (tid == 0) {
        float T = 0.0f; unsigned C = 0;
        #pragma unroll
        for (int x = 0; x < 4; ++x) { T += lt[x]; C += lc[x]; }
        atomicAdd(total, T);
        atomicAdd(count, C);
    }
}

__global__ void finalize_kernel(const float* __restrict__ total,
                                const unsigned* __restrict__ count,
                                float* __restrict__ out)
{
    out[0] = total[0] / fmaxf((float)count[0], 1.0f);
}

// =====================================================================
// Workspace layout (~4.5 MB):
//   [0,8)        : total (f32), count (u32)
//   [1024, ...)  : n1[4096], n2[4096], dpos[4096]  (f32)
//   [131072, ..) : e1q 4096x512 fp8 (2MB), then e2q (2MB)
// =====================================================================
extern "C" void kernel_launch(void* const* d_in, const int* in_sizes, int n_in,
                              void* d_out, int out_size, void* d_ws, size_t ws_size,
                              hipStream_t stream) {
    const float* e1 = (const float*)d_in[0];
    const float* e2 = (const float*)d_in[1];
    char* ws = (char*)d_ws;

    float*    total = (float*)ws;
    unsigned* count = (unsigned*)(ws + 4);
    float* n1   = (float*)(ws + 1024);
    float* n2   = n1 + 4096;
    float* dpos = n2 + 4096;
    unsigned* e1q = (unsigned*)(ws + (1 << 17));
    unsigned* e2q = e1q + (size_t)4096 * 128;

    hipMemsetAsync(ws, 0, 64, stream);
    prep_kernel<<<4096, 128, 0, stream>>>(e1, e2, e1q, e2q, n1, n2, dpos);
    triplet_main<<<544, 256, 0, stream>>>((const unsigned char*)e1q,
                                          (const unsigned char*)e2q,
                                          n1, n2, dpos, total, count);
    finalize_kernel<<<1, 1, 0, stream>>>(total, count, (float*)d_out);
}